// Round 5
// baseline (1064.793 us; speedup 1.0000x reference)
//
// ============================================================================
// DIAGNOSTIC ROUND: every kernel body is wrapped in an idempotent REP-loop so
// its single dispatch exceeds the ~160us harness fills and shows up in the
// rocprof top-5 WITH counters. True per-kernel cost = dur_us / REP_*.
// Strip REP_* back to 1 next round once per-kernel costs are known.
// ============================================================================
#include <hip/hip_runtime.h>
#include <stdint.h>

#define NB 4
#define NN 8192
#define NE 2048
#define NC 64
#define KS2 8              // n-split for k_edge2
#define NW8 (NN / 8)       // 1024 blocked-n groups
#define EW8 (NE / 8)       // 256 blocked-e groups

#define REP_T 24
#define REP_P 5
#define REP_E 20
#define REP_N 20

typedef __bf16 bf16x8 __attribute__((ext_vector_type(8)));
typedef float f32x16 __attribute__((ext_vector_type(16)));
typedef unsigned long long u64;

__device__ __forceinline__ unsigned short f2bf(float f) {
  union { float f; uint32_t u; } v; v.f = f;
  return (unsigned short)((v.u + 0x7FFFu + ((v.u >> 16) & 1u)) >> 16);
}
__device__ __forceinline__ bf16x8 ld_bf8(const void* p) { return *(const bf16x8*)p; }

// in-register 64x64 bit-matrix transpose across the wave
__device__ __forceinline__ u64 bt_step(u64 x, int k, u64 M1, int lane) {
  const u64 y = (u64)__shfl_xor((long long)x, k, 64);
  const u64 M0 = ~M1;
  return ((lane & k) == 0) ? ((x & M0) | ((y & M0) << k))
                           : ((x & M1) | ((y >> k) & M0));
}
__device__ __forceinline__ u64 bit_transpose64(u64 x, int lane) {
  x = bt_step(x, 1,  0xAAAAAAAAAAAAAAAAull, lane);
  x = bt_step(x, 2,  0xCCCCCCCCCCCCCCCCull, lane);
  x = bt_step(x, 4,  0xF0F0F0F0F0F0F0F0ull, lane);
  x = bt_step(x, 8,  0xFF00FF00FF00FF00ull, lane);
  x = bt_step(x, 16, 0xFFFF0000FFFF0000ull, lane);
  x = bt_step(x, 32, 0xFFFFFFFF00000000ull, lane);
  return x;
}

// 256-entry LDS LUT: byte -> 8 bf16 of 0.0/1.0 (16B). One ds_read_b128/frag.
#define LUT_INIT(lut)                                                     \
  {                                                                       \
    union { uint32_t u[4]; uint4 v; } e_;                                 \
    const uint32_t by_ = threadIdx.x & 255;                               \
    _Pragma("unroll")                                                     \
    for (int p_ = 0; p_ < 4; ++p_) {                                      \
      const uint32_t t_ = (by_ >> (2 * p_)) & 3u;                         \
      e_.u[p_] = (t_ & 1u) * 0x3F80u + (t_ & 2u) * 0x1FC00000u;           \
    }                                                                     \
    lut[by_] = e_.v;                                                      \
  }

// ---------------------------------------------------------------------------
// K1: x' = x @ theta (fp32), output BLOCKED bf16: xt_blk[b][n>>3][o][n&7].
// ---------------------------------------------------------------------------
__global__ __launch_bounds__(256) void k_transform(
    const float* __restrict__ x, const float* __restrict__ theta,
    unsigned short* __restrict__ xt_blk) {
  const int b = blockIdx.y, ns = blockIdx.x;
  const int n0 = ns * 64;
  __shared__ float xs[64][65];
  __shared__ float th[64][64];
  const int tid = threadIdx.x, w = tid >> 6, l = tid & 63;
  for (int rep = 0; rep < REP_T; ++rep) {
    asm volatile("" ::: "memory");
    for (int k = tid; k < 4096; k += 256) th[k >> 6][k & 63] = theta[k];
    const float* xrow = x + ((size_t)b * NN + n0) * NC;
    for (int k = tid; k < 4096; k += 256) xs[k >> 6][k & 63] = xrow[k];
    __syncthreads();
    float acc[16];
    #pragma unroll
    for (int j = 0; j < 16; ++j) acc[j] = 0.f;
    #pragma unroll 4
    for (int i = 0; i < 64; ++i) {
      const float xv = xs[l][i];
      const float4* t4 = (const float4*)(&th[i][w * 16]);
      const float4 a0 = t4[0], a1 = t4[1], a2 = t4[2], a3 = t4[3];
      acc[0]  += xv * a0.x; acc[1]  += xv * a0.y; acc[2]  += xv * a0.z; acc[3]  += xv * a0.w;
      acc[4]  += xv * a1.x; acc[5]  += xv * a1.y; acc[6]  += xv * a1.z; acc[7]  += xv * a1.w;
      acc[8]  += xv * a2.x; acc[9]  += xv * a2.y; acc[10] += xv * a2.z; acc[11] += xv * a2.w;
      acc[12] += xv * a3.x; acc[13] += xv * a3.y; acc[14] += xv * a3.z; acc[15] += xv * a3.w;
    }
    __syncthreads();                       // xs reads complete
    unsigned short* ost = (unsigned short*)&xs[0][0];   // reuse as [n][o] u16
    #pragma unroll
    for (int j = 0; j < 16; ++j) ost[l * 64 + w * 16 + j] = f2bf(acc[j]);
    __syncthreads();
    unsigned short* obase = xt_blk + ((size_t)b * NW8 + ns * 8) * 512;
    for (int c = tid; c < 512; c += 256) {   // c = g*64 + o
      const int g = c >> 6, o = c & 63;
      union { unsigned short s[8]; uint4 v; } pk;
      #pragma unroll
      for (int k = 0; k < 8; ++k) pk.s[k] = ost[(g * 8 + k) * 64 + o];
      *(uint4*)(obase + (size_t)c * 8) = pk.v;
    }
    __syncthreads();                       // before next rep rewrites xs
  }
}

// ---------------------------------------------------------------------------
// K_pack: streams H once; block = (64 rows, ALL e). Wave w: e-floats
// [w*512, w*512+512) as two 1KB chunks; 4-row prefetch. Emits bitsN
// [b][n>>6][e_nat] and bitsE [b][ew'][n] (e' = permuted order; bijection
// carried consistently: e_nat = (ew'>>3)*512 + ((ew'>>2)&1)*256 + 4t + (ew'&3)).
// ---------------------------------------------------------------------------
__global__ __launch_bounds__(256) void k_pack(
    const float* __restrict__ H, u64* __restrict__ bitsN,
    u64* __restrict__ bitsE) {
  const int ns = blockIdx.x, b = blockIdx.y;
  const int w = threadIdx.x >> 6, l = threadIdx.x & 63;
  const int n0 = ns * 64;
  const float* Hb = H + ((size_t)b * NN + n0) * NE + w * 512 + 4 * l;
  u64* bn = bitsN + ((size_t)b * 128 + ns) * NE + w * 512 + 4 * l;
  u64* be = bitsE + (size_t)b * 32 * NN + n0 + l;
  const u64 top = 0x8000000000000000ull;

  for (int rep = 0; rep < REP_P; ++rep) {
    asm volatile("" ::: "memory");
    u64 wn[8];
    #pragma unroll
    for (int i = 0; i < 8; ++i) wn[i] = 0;
    float4 pA[4], pB[4];
    #pragma unroll
    for (int j = 0; j < 4; ++j) {
      pA[j] = *(const float4*)(Hb + (size_t)j * NE);
      pB[j] = *(const float4*)(Hb + (size_t)j * NE + 256);
    }
    #pragma unroll 4
    for (int r = 0; r < 64; ++r) {
      const float4 a = pA[r & 3], c = pB[r & 3];
      if (r + 4 < 64) {
        pA[r & 3] = *(const float4*)(Hb + (size_t)(r + 4) * NE);
        pB[r & 3] = *(const float4*)(Hb + (size_t)(r + 4) * NE + 256);
      }
      wn[0] = (wn[0] >> 1) | (a.x != 0.f ? top : 0);
      wn[1] = (wn[1] >> 1) | (a.y != 0.f ? top : 0);
      wn[2] = (wn[2] >> 1) | (a.z != 0.f ? top : 0);
      wn[3] = (wn[3] >> 1) | (a.w != 0.f ? top : 0);
      wn[4] = (wn[4] >> 1) | (c.x != 0.f ? top : 0);
      wn[5] = (wn[5] >> 1) | (c.y != 0.f ? top : 0);
      wn[6] = (wn[6] >> 1) | (c.z != 0.f ? top : 0);
      wn[7] = (wn[7] >> 1) | (c.w != 0.f ? top : 0);
    }
    // bitsN: chunk A words at e=4l+i, chunk B at +256 (32B per chunk per lane)
    *(ulonglong2*)(bn + 0)   = make_ulonglong2(wn[0], wn[1]);
    *(ulonglong2*)(bn + 2)   = make_ulonglong2(wn[2], wn[3]);
    *(ulonglong2*)(bn + 256) = make_ulonglong2(wn[4], wn[5]);
    *(ulonglong2*)(bn + 258) = make_ulonglong2(wn[6], wn[7]);
    // bitsE: transpose -> word ew' = w*8+i, lane holds node n0+l
    #pragma unroll
    for (int i = 0; i < 8; ++i)
      be[(size_t)(w * 8 + i) * NN] = bit_transpose64(wn[i], l);
  }
}

// ---------------------------------------------------------------------------
// K_edge2: D[e' 64][o 64] += H^T[e'][n] * x'[n][o].  A = bitsN via LDS-LUT
// (contig 256B u64 loads... strided by perm, 16 lines/instr), B = xt_blk
// contiguous 16B frags. No barriers in the loop. deg_e via popcount.
// ---------------------------------------------------------------------------
__global__ __launch_bounds__(256) void k_edge2(
    const u64* __restrict__ bitsN, const unsigned short* __restrict__ xt_blk,
    float* __restrict__ xe_part, float* __restrict__ deg_part) {
  const int ew = blockIdx.x, b = blockIdx.y, ks = blockIdx.z;
  const int tid = threadIdx.x, w = tid >> 6, l = tid & 63, q = l >> 5;
  __shared__ uint4 lut[256];
  LUT_INIT(lut)
  __syncthreads();
  const int erow = (w & 1) * 32 + (l & 31);
  const int ocol = (w >> 1) * 32 + (l & 31);
  const int enat = (ew >> 3) * 512 + ((ew >> 2) & 1) * 256 + 4 * erow + (ew & 3);
  const u64* Nb = bitsN + ((size_t)b * 128 + ks * 16) * NE + enat;
  const unsigned short* Bb =
      xt_blk + ((size_t)b * NW8 + ks * 128) * 512 + (size_t)ocol * 8;
  float* xo = xe_part + ((size_t)(ks * NB + b)) * (NE * NC) +
              (size_t)ew * 64 * NC + ocol;

  for (int rep = 0; rep < REP_E; ++rep) {
    asm volatile("" ::: "memory");
    f32x16 acc;
    #pragma unroll
    for (int j = 0; j < 16; ++j) acc[j] = 0.f;
    int dcount = 0;
    for (int nt = 0; nt < 16; ++nt) {
      const u64 wbits = Nb[(size_t)nt * NE];
      dcount += __popcll(wbits);
      #pragma unroll
      for (int kk = 0; kk < 4; ++kk) {
        const bf16x8 av =
            *(const bf16x8*)&lut[(uint32_t)(wbits >> (8 * (kk * 2 + q))) & 0xFFu];
        const bf16x8 bv = ld_bf8(Bb + (size_t)(nt * 8 + kk * 2 + q) * 512);
        acc = __builtin_amdgcn_mfma_f32_32x32x16_bf16(av, bv, acc, 0, 0, 0);
      }
    }
    #pragma unroll
    for (int r = 0; r < 16; ++r) {
      const int rho = (w & 1) * 32 + 4 * q + (r & 3) + 8 * (r >> 2);
      xo[(size_t)rho * NC] = acc[r];
    }
    if (w < 2 && q == 0)
      deg_part[(size_t)(ks * NB + b) * NE + ew * 64 + erow] = (float)dcount;
  }
}

// ---------------------------------------------------------------------------
// K_deg: deg_inv[b][e'] = 1 / sum_ks deg_part.
// ---------------------------------------------------------------------------
__global__ __launch_bounds__(256) void k_deg(
    const float* __restrict__ deg_part, float* __restrict__ deg_inv) {
  const int idx = blockIdx.x * 256 + threadIdx.x;
  float s = 0.f;
  #pragma unroll
  for (int ks = 0; ks < KS2; ++ks) s += deg_part[(size_t)ks * (NB * NE) + idx];
  deg_inv[idx] = s > 0.f ? 1.0f / s : 0.f;
}

// ---------------------------------------------------------------------------
// K_edge_norm: xe_blk[b][e'>>3][o][e'&7] = bf16(sum_ks xe_part * deg_inv).
// Coalesced reads -> LDS transpose -> coalesced blocked writes.
// ---------------------------------------------------------------------------
__global__ __launch_bounds__(256) void k_edge_norm(
    const float* __restrict__ xe_part, const float* __restrict__ deg_inv,
    unsigned short* __restrict__ xe_blk) {
  const int eb = blockIdx.x, b = blockIdx.y, tid = threadIdx.x;
  __shared__ unsigned short tt[64][72];
  const int o = tid & 63, eg = tid >> 6;
  #pragma unroll 4
  for (int j = 0; j < 16; ++j) {
    const int el = eg * 16 + j;
    const size_t idx = ((size_t)b * NE + eb * 64 + el) * NC + o;
    float s = 0.f;
    #pragma unroll
    for (int ks = 0; ks < KS2; ++ks) s += xe_part[(size_t)ks * (NB * NE * NC) + idx];
    tt[el][o] = f2bf(s * deg_inv[b * NE + eb * 64 + el]);
  }
  __syncthreads();
  unsigned short* obase = xe_blk + ((size_t)b * EW8 + eb * 8) * 512;
  for (int c = tid; c < 512; c += 256) {
    const int g = c >> 6, oo = c & 63;
    union { unsigned short s[8]; uint4 v; } pk;
    #pragma unroll
    for (int k = 0; k < 8; ++k) pk.s[k] = tt[g * 8 + k][oo];
    *(uint4*)(obase + (size_t)c * 8) = pk.v;
  }
}

// ---------------------------------------------------------------------------
// K_node2: D[n 64][o 64] += H[n][e'] * xe[e'][o].  A = bitsE via LDS-LUT
// (256B contig u64 loads), B = xe_blk contiguous frags. deg_n via popcount.
// ---------------------------------------------------------------------------
__global__ __launch_bounds__(256) void k_node2(
    const u64* __restrict__ bitsE, const unsigned short* __restrict__ xe_blk,
    const float* __restrict__ bias, float* __restrict__ out) {
  const int ns = blockIdx.x, b = blockIdx.y;
  const int n0 = ns * 64;
  const int tid = threadIdx.x, w = tid >> 6, l = tid & 63, q = l >> 5;
  __shared__ uint4 lut[256];
  __shared__ float ldsDeg[64];
  LUT_INIT(lut)
  const int arow = (w & 1) * 32 + (l & 31);
  const int ocol = (w >> 1) * 32 + (l & 31);
  const u64* Eb = bitsE + (size_t)b * 32 * NN + n0 + arow;
  const unsigned short* Bb = xe_blk + (size_t)b * EW8 * 512 + (size_t)ocol * 8;
  __syncthreads();

  for (int rep = 0; rep < REP_N; ++rep) {
    asm volatile("" ::: "memory");
    f32x16 acc;
    #pragma unroll
    for (int j = 0; j < 16; ++j) acc[j] = 0.f;
    int dcount = 0;
    for (int et = 0; et < 32; ++et) {
      const u64 wbits = Eb[(size_t)et * NN];
      dcount += __popcll(wbits);
      #pragma unroll
      for (int kk = 0; kk < 4; ++kk) {
        const bf16x8 av =
            *(const bf16x8*)&lut[(uint32_t)(wbits >> (8 * (kk * 2 + q))) & 0xFFu];
        const bf16x8 bv = ld_bf8(Bb + (size_t)(et * 8 + kk * 2 + q) * 512);
        acc = __builtin_amdgcn_mfma_f32_32x32x16_bf16(av, bv, acc, 0, 0, 0);
      }
    }
    if (w < 2 && q == 0) ldsDeg[arow] = dcount > 0 ? 1.0f / (float)dcount : 0.f;
    __syncthreads();
    const float bv0 = bias[ocol];
    #pragma unroll
    for (int r = 0; r < 16; ++r) {
      const int rho = (w & 1) * 32 + 4 * q + (r & 3) + 8 * (r >> 2);
      out[((size_t)b * NN + n0 + rho) * NC + ocol] = acc[r] * ldsDeg[rho] + bv0;
    }
    __syncthreads();   // ldsDeg safe before next rep
  }
}

// ---------------------------------------------------------------------------
// ws: xt_blk @0 (4MB) | bitsN @4MB (8MB) | bitsE @12MB (8MB) | xe_part @20MB
// (16MB) | deg_part @36MB (256KB) | deg_inv @+256KB (32KB) | xe_blk @37MB (1MB)
// ---------------------------------------------------------------------------
extern "C" void kernel_launch(void* const* d_in, const int* in_sizes, int n_in,
                              void* d_out, int out_size, void* d_ws, size_t ws_size,
                              hipStream_t stream) {
  const float* x     = (const float*)d_in[0];
  const float* H     = (const float*)d_in[1];
  const float* theta = (const float*)d_in[2];
  const float* bias  = (const float*)d_in[3];
  float* out = (float*)d_out;
  char* ws = (char*)d_ws;

  unsigned short* xt_blk = (unsigned short*)ws;
  u64* bitsN             = (u64*)(ws + (4ull << 20));
  u64* bitsE             = (u64*)(ws + (12ull << 20));
  float* xe_part         = (float*)(ws + (20ull << 20));
  float* deg_part        = (float*)(ws + (36ull << 20));
  float* deg_inv         = (float*)(ws + (36ull << 20) + (256ull << 10));
  unsigned short* xe_blk = (unsigned short*)(ws + (37ull << 20));

  k_transform<<<dim3(NN / 64, NB), 256, 0, stream>>>(x, theta, xt_blk);
  k_pack<<<dim3(NN / 64, NB), 256, 0, stream>>>(H, bitsN, bitsE);
  k_edge2<<<dim3(32, NB, KS2), 256, 0, stream>>>(bitsN, xt_blk, xe_part, deg_part);
  k_deg<<<dim3((NB * NE) / 256), 256, 0, stream>>>(deg_part, deg_inv);
  k_edge_norm<<<dim3(NE / 64, NB), 256, 0, stream>>>(xe_part, deg_inv, xe_blk);
  k_node2<<<dim3(NN / 64, NB), 256, 0, stream>>>(bitsE, xe_blk, bias, out);
}

// Round 7
// 242.681 us; speedup vs baseline: 4.3876x; 4.3876x over previous
//
// ============================================================================
// Recovery round: all kernel bodies are byte-identical to the round-5 PASSING
// diagnostic build (absmax 2.441e-4); REP stripped everywhere EXCEPT k_pack
// (REP_P=4) — the dominant, never-directly-measured kernel. True k_pack cost
// = dur/4; true pipeline total = dur_us - 3*(k_pack dur/4).
// ============================================================================
#include <hip/hip_runtime.h>
#include <stdint.h>

#define NB 4
#define NN 8192
#define NE 2048
#define NC 64
#define KS2 8              // n-split for k_edge2
#define NW8 (NN / 8)       // 1024 blocked-n groups
#define EW8 (NE / 8)       // 256 blocked-e groups

#define REP_P 4

typedef __bf16 bf16x8 __attribute__((ext_vector_type(8)));
typedef float f32x16 __attribute__((ext_vector_type(16)));
typedef unsigned long long u64;

__device__ __forceinline__ unsigned short f2bf(float f) {
  union { float f; uint32_t u; } v; v.f = f;
  return (unsigned short)((v.u + 0x7FFFu + ((v.u >> 16) & 1u)) >> 16);
}
__device__ __forceinline__ bf16x8 ld_bf8(const void* p) { return *(const bf16x8*)p; }

// in-register 64x64 bit-matrix transpose across the wave
__device__ __forceinline__ u64 bt_step(u64 x, int k, u64 M1, int lane) {
  const u64 y = (u64)__shfl_xor((long long)x, k, 64);
  const u64 M0 = ~M1;
  return ((lane & k) == 0) ? ((x & M0) | ((y & M0) << k))
                           : ((x & M1) | ((y >> k) & M0));
}
__device__ __forceinline__ u64 bit_transpose64(u64 x, int lane) {
  x = bt_step(x, 1,  0xAAAAAAAAAAAAAAAAull, lane);
  x = bt_step(x, 2,  0xCCCCCCCCCCCCCCCCull, lane);
  x = bt_step(x, 4,  0xF0F0F0F0F0F0F0F0ull, lane);
  x = bt_step(x, 8,  0xFF00FF00FF00FF00ull, lane);
  x = bt_step(x, 16, 0xFFFF0000FFFF0000ull, lane);
  x = bt_step(x, 32, 0xFFFFFFFF00000000ull, lane);
  return x;
}

// 256-entry LDS LUT: byte -> 8 bf16 of 0.0/1.0 (16B).
#define LUT_INIT(lut)                                                     \
  {                                                                       \
    union { uint32_t u[4]; uint4 v; } e_;                                 \
    const uint32_t by_ = threadIdx.x & 255;                               \
    _Pragma("unroll")                                                     \
    for (int p_ = 0; p_ < 4; ++p_) {                                      \
      const uint32_t t_ = (by_ >> (2 * p_)) & 3u;                         \
      e_.u[p_] = (t_ & 1u) * 0x3F80u + (t_ & 2u) * 0x1FC00000u;           \
    }                                                                     \
    lut[by_] = e_.v;                                                      \
  }

// ---------------------------------------------------------------------------
// K1: x' = x @ theta (fp32), output BLOCKED bf16: xt_blk[b][n>>3][o][n&7].
// (round-5 verified body, REP stripped)
// ---------------------------------------------------------------------------
__global__ __launch_bounds__(256) void k_transform(
    const float* __restrict__ x, const float* __restrict__ theta,
    unsigned short* __restrict__ xt_blk) {
  const int b = blockIdx.y, ns = blockIdx.x;
  const int n0 = ns * 64;
  __shared__ float xs[64][65];
  __shared__ float th[64][64];
  const int tid = threadIdx.x, w = tid >> 6, l = tid & 63;
  for (int k = tid; k < 4096; k += 256) th[k >> 6][k & 63] = theta[k];
  const float* xrow = x + ((size_t)b * NN + n0) * NC;
  for (int k = tid; k < 4096; k += 256) xs[k >> 6][k & 63] = xrow[k];
  __syncthreads();
  float acc[16];
  #pragma unroll
  for (int j = 0; j < 16; ++j) acc[j] = 0.f;
  #pragma unroll 4
  for (int i = 0; i < 64; ++i) {
    const float xv = xs[l][i];
    const float4* t4 = (const float4*)(&th[i][w * 16]);
    const float4 a0 = t4[0], a1 = t4[1], a2 = t4[2], a3 = t4[3];
    acc[0]  += xv * a0.x; acc[1]  += xv * a0.y; acc[2]  += xv * a0.z; acc[3]  += xv * a0.w;
    acc[4]  += xv * a1.x; acc[5]  += xv * a1.y; acc[6]  += xv * a1.z; acc[7]  += xv * a1.w;
    acc[8]  += xv * a2.x; acc[9]  += xv * a2.y; acc[10] += xv * a2.z; acc[11] += xv * a2.w;
    acc[12] += xv * a3.x; acc[13] += xv * a3.y; acc[14] += xv * a3.z; acc[15] += xv * a3.w;
  }
  __syncthreads();                       // xs reads complete
  unsigned short* ost = (unsigned short*)&xs[0][0];   // reuse as [n][o] u16
  #pragma unroll
  for (int j = 0; j < 16; ++j) ost[l * 64 + w * 16 + j] = f2bf(acc[j]);
  __syncthreads();
  unsigned short* obase = xt_blk + ((size_t)b * NW8 + ns * 8) * 512;
  for (int c = tid; c < 512; c += 256) {   // c = g*64 + o
    const int g = c >> 6, o = c & 63;
    union { unsigned short s[8]; uint4 v; } pk;
    #pragma unroll
    for (int k = 0; k < 8; ++k) pk.s[k] = ost[(g * 8 + k) * 64 + o];
    *(uint4*)(obase + (size_t)c * 8) = pk.v;
  }
}

// ---------------------------------------------------------------------------
// K_pack: streams H once (round-5 verified body). REP_P=4 instrumentation to
// surface its counters above the ~160us harness fills. Idempotent.
// ---------------------------------------------------------------------------
__global__ __launch_bounds__(256) void k_pack(
    const float* __restrict__ H, u64* __restrict__ bitsN,
    u64* __restrict__ bitsE) {
  const int ns = blockIdx.x, b = blockIdx.y;
  const int w = threadIdx.x >> 6, l = threadIdx.x & 63;
  const int n0 = ns * 64;
  const float* Hb = H + ((size_t)b * NN + n0) * NE + w * 512 + 4 * l;
  u64* bn = bitsN + ((size_t)b * 128 + ns) * NE + w * 512 + 4 * l;
  u64* be = bitsE + (size_t)b * 32 * NN + n0 + l;
  const u64 top = 0x8000000000000000ull;

  for (int rep = 0; rep < REP_P; ++rep) {
    asm volatile("" ::: "memory");
    u64 wn[8];
    #pragma unroll
    for (int i = 0; i < 8; ++i) wn[i] = 0;
    float4 pA[4], pB[4];
    #pragma unroll
    for (int j = 0; j < 4; ++j) {
      pA[j] = *(const float4*)(Hb + (size_t)j * NE);
      pB[j] = *(const float4*)(Hb + (size_t)j * NE + 256);
    }
    #pragma unroll 4
    for (int r = 0; r < 64; ++r) {
      const float4 a = pA[r & 3], c = pB[r & 3];
      if (r + 4 < 64) {
        pA[r & 3] = *(const float4*)(Hb + (size_t)(r + 4) * NE);
        pB[r & 3] = *(const float4*)(Hb + (size_t)(r + 4) * NE + 256);
      }
      wn[0] = (wn[0] >> 1) | (a.x != 0.f ? top : 0);
      wn[1] = (wn[1] >> 1) | (a.y != 0.f ? top : 0);
      wn[2] = (wn[2] >> 1) | (a.z != 0.f ? top : 0);
      wn[3] = (wn[3] >> 1) | (a.w != 0.f ? top : 0);
      wn[4] = (wn[4] >> 1) | (c.x != 0.f ? top : 0);
      wn[5] = (wn[5] >> 1) | (c.y != 0.f ? top : 0);
      wn[6] = (wn[6] >> 1) | (c.z != 0.f ? top : 0);
      wn[7] = (wn[7] >> 1) | (c.w != 0.f ? top : 0);
    }
    *(ulonglong2*)(bn + 0)   = make_ulonglong2(wn[0], wn[1]);
    *(ulonglong2*)(bn + 2)   = make_ulonglong2(wn[2], wn[3]);
    *(ulonglong2*)(bn + 256) = make_ulonglong2(wn[4], wn[5]);
    *(ulonglong2*)(bn + 258) = make_ulonglong2(wn[6], wn[7]);
    #pragma unroll
    for (int i = 0; i < 8; ++i)
      be[(size_t)(w * 8 + i) * NN] = bit_transpose64(wn[i], l);
  }
}

// ---------------------------------------------------------------------------
// K_edge2: D[e' 64][o 64] += H^T[e'][n] * x'[n][o]. (round-5 verified body,
// REP stripped). A = bitsN via LDS-LUT, B = xt_blk contiguous 16B frags.
// ---------------------------------------------------------------------------
__global__ __launch_bounds__(256) void k_edge2(
    const u64* __restrict__ bitsN, const unsigned short* __restrict__ xt_blk,
    float* __restrict__ xe_part, float* __restrict__ deg_part) {
  const int ew = blockIdx.x, b = blockIdx.y, ks = blockIdx.z;
  const int tid = threadIdx.x, w = tid >> 6, l = tid & 63, q = l >> 5;
  __shared__ uint4 lut[256];
  LUT_INIT(lut)
  __syncthreads();
  const int erow = (w & 1) * 32 + (l & 31);
  const int ocol = (w >> 1) * 32 + (l & 31);
  const int enat = (ew >> 3) * 512 + ((ew >> 2) & 1) * 256 + 4 * erow + (ew & 3);
  const u64* Nb = bitsN + ((size_t)b * 128 + ks * 16) * NE + enat;
  const unsigned short* Bb =
      xt_blk + ((size_t)b * NW8 + ks * 128) * 512 + (size_t)ocol * 8;
  float* xo = xe_part + ((size_t)(ks * NB + b)) * (NE * NC) +
              (size_t)ew * 64 * NC + ocol;

  f32x16 acc;
  #pragma unroll
  for (int j = 0; j < 16; ++j) acc[j] = 0.f;
  int dcount = 0;
  for (int nt = 0; nt < 16; ++nt) {
    const u64 wbits = Nb[(size_t)nt * NE];
    dcount += __popcll(wbits);
    #pragma unroll
    for (int kk = 0; kk < 4; ++kk) {
      const bf16x8 av =
          *(const bf16x8*)&lut[(uint32_t)(wbits >> (8 * (kk * 2 + q))) & 0xFFu];
      const bf16x8 bv = ld_bf8(Bb + (size_t)(nt * 8 + kk * 2 + q) * 512);
      acc = __builtin_amdgcn_mfma_f32_32x32x16_bf16(av, bv, acc, 0, 0, 0);
    }
  }
  #pragma unroll
  for (int r = 0; r < 16; ++r) {
    const int rho = (w & 1) * 32 + 4 * q + (r & 3) + 8 * (r >> 2);
    xo[(size_t)rho * NC] = acc[r];
  }
  if (w < 2 && q == 0)
    deg_part[(size_t)(ks * NB + b) * NE + ew * 64 + erow] = (float)dcount;
}

// ---------------------------------------------------------------------------
// K_deg: deg_inv[b][e'] = 1 / sum_ks deg_part.
// ---------------------------------------------------------------------------
__global__ __launch_bounds__(256) void k_deg(
    const float* __restrict__ deg_part, float* __restrict__ deg_inv) {
  const int idx = blockIdx.x * 256 + threadIdx.x;
  float s = 0.f;
  #pragma unroll
  for (int ks = 0; ks < KS2; ++ks) s += deg_part[(size_t)ks * (NB * NE) + idx];
  deg_inv[idx] = s > 0.f ? 1.0f / s : 0.f;
}

// ---------------------------------------------------------------------------
// K_edge_norm: xe_blk[b][e'>>3][o][e'&7] = bf16(sum_ks xe_part * deg_inv).
// ---------------------------------------------------------------------------
__global__ __launch_bounds__(256) void k_edge_norm(
    const float* __restrict__ xe_part, const float* __restrict__ deg_inv,
    unsigned short* __restrict__ xe_blk) {
  const int eb = blockIdx.x, b = blockIdx.y, tid = threadIdx.x;
  __shared__ unsigned short tt[64][72];
  const int o = tid & 63, eg = tid >> 6;
  #pragma unroll 4
  for (int j = 0; j < 16; ++j) {
    const int el = eg * 16 + j;
    const size_t idx = ((size_t)b * NE + eb * 64 + el) * NC + o;
    float s = 0.f;
    #pragma unroll
    for (int ks = 0; ks < KS2; ++ks) s += xe_part[(size_t)ks * (NB * NE * NC) + idx];
    tt[el][o] = f2bf(s * deg_inv[b * NE + eb * 64 + el]);
  }
  __syncthreads();
  unsigned short* obase = xe_blk + ((size_t)b * EW8 + eb * 8) * 512;
  for (int c = tid; c < 512; c += 256) {
    const int g = c >> 6, oo = c & 63;
    union { unsigned short s[8]; uint4 v; } pk;
    #pragma unroll
    for (int k = 0; k < 8; ++k) pk.s[k] = tt[g * 8 + k][oo];
    *(uint4*)(obase + (size_t)c * 8) = pk.v;
  }
}

// ---------------------------------------------------------------------------
// K_node2: D[n 64][o 64] += H[n][e'] * xe[e'][o]. (round-5 verified body,
// REP stripped). A = bitsE via LDS-LUT, B = xe_blk frags. deg_n = popcount.
// ---------------------------------------------------------------------------
__global__ __launch_bounds__(256) void k_node2(
    const u64* __restrict__ bitsE, const unsigned short* __restrict__ xe_blk,
    const float* __restrict__ bias, float* __restrict__ out) {
  const int ns = blockIdx.x, b = blockIdx.y;
  const int n0 = ns * 64;
  const int tid = threadIdx.x, w = tid >> 6, l = tid & 63, q = l >> 5;
  __shared__ uint4 lut[256];
  __shared__ float ldsDeg[64];
  LUT_INIT(lut)
  const int arow = (w & 1) * 32 + (l & 31);
  const int ocol = (w >> 1) * 32 + (l & 31);
  const u64* Eb = bitsE + (size_t)b * 32 * NN + n0 + arow;
  const unsigned short* Bb = xe_blk + (size_t)b * EW8 * 512 + (size_t)ocol * 8;
  __syncthreads();

  f32x16 acc;
  #pragma unroll
  for (int j = 0; j < 16; ++j) acc[j] = 0.f;
  int dcount = 0;
  for (int et = 0; et < 32; ++et) {
    const u64 wbits = Eb[(size_t)et * NN];
    dcount += __popcll(wbits);
    #pragma unroll
    for (int kk = 0; kk < 4; ++kk) {
      const bf16x8 av =
          *(const bf16x8*)&lut[(uint32_t)(wbits >> (8 * (kk * 2 + q))) & 0xFFu];
      const bf16x8 bv = ld_bf8(Bb + (size_t)(et * 8 + kk * 2 + q) * 512);
      acc = __builtin_amdgcn_mfma_f32_32x32x16_bf16(av, bv, acc, 0, 0, 0);
    }
  }
  if (w < 2 && q == 0) ldsDeg[arow] = dcount > 0 ? 1.0f / (float)dcount : 0.f;
  __syncthreads();
  const float bv0 = bias[ocol];
  #pragma unroll
  for (int r = 0; r < 16; ++r) {
    const int rho = (w & 1) * 32 + 4 * q + (r & 3) + 8 * (r >> 2);
    out[((size_t)b * NN + n0 + rho) * NC + ocol] = acc[r] * ldsDeg[rho] + bv0;
  }
}

// ---------------------------------------------------------------------------
// ws: xt_blk @0 (4MB) | bitsN @4MB (8MB) | bitsE @12MB (8MB) | xe_part @20MB
// (16MB) | deg_part @36MB (256KB) | deg_inv @+256KB (32KB) | xe_blk @37MB (1MB)
// Extent 38MB (proven in rounds 3-5).
// ---------------------------------------------------------------------------
extern "C" void kernel_launch(void* const* d_in, const int* in_sizes, int n_in,
                              void* d_out, int out_size, void* d_ws, size_t ws_size,
                              hipStream_t stream) {
  const float* x     = (const float*)d_in[0];
  const float* H     = (const float*)d_in[1];
  const float* theta = (const float*)d_in[2];
  const float* bias  = (const float*)d_in[3];
  float* out = (float*)d_out;
  char* ws = (char*)d_ws;

  unsigned short* xt_blk = (unsigned short*)ws;
  u64* bitsN             = (u64*)(ws + (4ull << 20));
  u64* bitsE             = (u64*)(ws + (12ull << 20));
  float* xe_part         = (float*)(ws + (20ull << 20));
  float* deg_part        = (float*)(ws + (36ull << 20));
  float* deg_inv         = (float*)(ws + (36ull << 20) + (256ull << 10));
  unsigned short* xe_blk = (unsigned short*)(ws + (37ull << 20));

  k_transform<<<dim3(NN / 64, NB), 256, 0, stream>>>(x, theta, xt_blk);
  k_pack<<<dim3(NN / 64, NB), 256, 0, stream>>>(H, bitsN, bitsE);
  k_edge2<<<dim3(32, NB, KS2), 256, 0, stream>>>(bitsN, xt_blk, xe_part, deg_part);
  k_deg<<<dim3((NB * NE) / 256), 256, 0, stream>>>(deg_part, deg_inv);
  k_edge_norm<<<dim3(NE / 64, NB), 256, 0, stream>>>(xe_part, deg_inv, xe_blk);
  k_node2<<<dim3(NN / 64, NB), 256, 0, stream>>>(bitsE, xe_blk, bias, out);
}

// Round 8
// 156.998 us; speedup vs baseline: 6.7822x; 1.5458x over previous
//
// ============================================================================
// Round 8: k_pack occupancy attack (512 -> 2048 blocks, float2/lane, lower
// VGPR). bitsN bytes unchanged; bitsE e'-permutation changed consistently
// with k_edge2's enat line (the ONLY consumer of the permutation). All other
// kernels byte-identical to the passing round-7 build. REP_P=4 retained on
// k_pack for counter visibility (true cost = dur/4).
// ============================================================================
#include <hip/hip_runtime.h>
#include <stdint.h>

#define NB 4
#define NN 8192
#define NE 2048
#define NC 64
#define KS2 8              // n-split for k_edge2
#define NW8 (NN / 8)       // 1024 blocked-n groups
#define EW8 (NE / 8)       // 256 blocked-e groups

#define REP_P 4

typedef __bf16 bf16x8 __attribute__((ext_vector_type(8)));
typedef float f32x16 __attribute__((ext_vector_type(16)));
typedef unsigned long long u64;

__device__ __forceinline__ unsigned short f2bf(float f) {
  union { float f; uint32_t u; } v; v.f = f;
  return (unsigned short)((v.u + 0x7FFFu + ((v.u >> 16) & 1u)) >> 16);
}
__device__ __forceinline__ bf16x8 ld_bf8(const void* p) { return *(const bf16x8*)p; }

// in-register 64x64 bit-matrix transpose across the wave
__device__ __forceinline__ u64 bt_step(u64 x, int k, u64 M1, int lane) {
  const u64 y = (u64)__shfl_xor((long long)x, k, 64);
  const u64 M0 = ~M1;
  return ((lane & k) == 0) ? ((x & M0) | ((y & M0) << k))
                           : ((x & M1) | ((y >> k) & M0));
}
__device__ __forceinline__ u64 bit_transpose64(u64 x, int lane) {
  x = bt_step(x, 1,  0xAAAAAAAAAAAAAAAAull, lane);
  x = bt_step(x, 2,  0xCCCCCCCCCCCCCCCCull, lane);
  x = bt_step(x, 4,  0xF0F0F0F0F0F0F0F0ull, lane);
  x = bt_step(x, 8,  0xFF00FF00FF00FF00ull, lane);
  x = bt_step(x, 16, 0xFFFF0000FFFF0000ull, lane);
  x = bt_step(x, 32, 0xFFFFFFFF00000000ull, lane);
  return x;
}

// 256-entry LDS LUT: byte -> 8 bf16 of 0.0/1.0 (16B).
#define LUT_INIT(lut)                                                     \
  {                                                                       \
    union { uint32_t u[4]; uint4 v; } e_;                                 \
    const uint32_t by_ = threadIdx.x & 255;                               \
    _Pragma("unroll")                                                     \
    for (int p_ = 0; p_ < 4; ++p_) {                                      \
      const uint32_t t_ = (by_ >> (2 * p_)) & 3u;                         \
      e_.u[p_] = (t_ & 1u) * 0x3F80u + (t_ & 2u) * 0x1FC00000u;           \
    }                                                                     \
    lut[by_] = e_.v;                                                      \
  }

// ---------------------------------------------------------------------------
// K1: x' = x @ theta (fp32), output BLOCKED bf16: xt_blk[b][n>>3][o][n&7].
// (round-7 verified body, unchanged)
// ---------------------------------------------------------------------------
__global__ __launch_bounds__(256) void k_transform(
    const float* __restrict__ x, const float* __restrict__ theta,
    unsigned short* __restrict__ xt_blk) {
  const int b = blockIdx.y, ns = blockIdx.x;
  const int n0 = ns * 64;
  __shared__ float xs[64][65];
  __shared__ float th[64][64];
  const int tid = threadIdx.x, w = tid >> 6, l = tid & 63;
  for (int k = tid; k < 4096; k += 256) th[k >> 6][k & 63] = theta[k];
  const float* xrow = x + ((size_t)b * NN + n0) * NC;
  for (int k = tid; k < 4096; k += 256) xs[k >> 6][k & 63] = xrow[k];
  __syncthreads();
  float acc[16];
  #pragma unroll
  for (int j = 0; j < 16; ++j) acc[j] = 0.f;
  #pragma unroll 4
  for (int i = 0; i < 64; ++i) {
    const float xv = xs[l][i];
    const float4* t4 = (const float4*)(&th[i][w * 16]);
    const float4 a0 = t4[0], a1 = t4[1], a2 = t4[2], a3 = t4[3];
    acc[0]  += xv * a0.x; acc[1]  += xv * a0.y; acc[2]  += xv * a0.z; acc[3]  += xv * a0.w;
    acc[4]  += xv * a1.x; acc[5]  += xv * a1.y; acc[6]  += xv * a1.z; acc[7]  += xv * a1.w;
    acc[8]  += xv * a2.x; acc[9]  += xv * a2.y; acc[10] += xv * a2.z; acc[11] += xv * a2.w;
    acc[12] += xv * a3.x; acc[13] += xv * a3.y; acc[14] += xv * a3.z; acc[15] += xv * a3.w;
  }
  __syncthreads();                       // xs reads complete
  unsigned short* ost = (unsigned short*)&xs[0][0];   // reuse as [n][o] u16
  #pragma unroll
  for (int j = 0; j < 16; ++j) ost[l * 64 + w * 16 + j] = f2bf(acc[j]);
  __syncthreads();
  unsigned short* obase = xt_blk + ((size_t)b * NW8 + ns * 8) * 512;
  for (int c = tid; c < 512; c += 256) {   // c = g*64 + o
    const int g = c >> 6, o = c & 63;
    union { unsigned short s[8]; uint4 v; } pk;
    #pragma unroll
    for (int k = 0; k < 8; ++k) pk.s[k] = ost[(g * 8 + k) * 64 + o];
    *(uint4*)(obase + (size_t)c * 8) = pk.v;
  }
}

// ---------------------------------------------------------------------------
// K_pack: streams H once. Grid 2048 blocks (8/CU): block = 64 rows x 512
// e-floats (eh quarter); wave = 128-float strip; lane = float2/row, 8-row
// prefetch. Emits bitsN[b][nw][e_nat] (bytes IDENTICAL to round 7) and
// bitsE[b][ew'][n] with e' permutation: e_nat = (ew'>>1)*128 + 2*bit + (ew'&1).
// REP_P=4 instrumented (idempotent).
// ---------------------------------------------------------------------------
__global__ __launch_bounds__(256) void k_pack(
    const float* __restrict__ H, u64* __restrict__ bitsN,
    u64* __restrict__ bitsE) {
  const int ns = blockIdx.x >> 2, eh = blockIdx.x & 3, b = blockIdx.y;
  const int w = threadIdx.x >> 6, l = threadIdx.x & 63;
  const int n0 = ns * 64;
  const int strip = eh * 4 + w;              // global 128-float strip [0,16)
  const float* Hb = H + ((size_t)b * NN + n0) * NE + strip * 128 + 2 * l;
  u64* bn = bitsN + ((size_t)b * 128 + ns) * NE + strip * 128 + 2 * l;
  u64* be = bitsE + (size_t)b * 32 * NN + n0 + l;
  const u64 top = 0x8000000000000000ull;

  for (int rep = 0; rep < REP_P; ++rep) {
    asm volatile("" ::: "memory");
    u64 wn0 = 0, wn1 = 0;
    float2 pf[8];
    #pragma unroll
    for (int j = 0; j < 8; ++j) pf[j] = *(const float2*)(Hb + (size_t)j * NE);
    #pragma unroll 8
    for (int r = 0; r < 56; ++r) {
      const float2 v = pf[r & 7];
      pf[r & 7] = *(const float2*)(Hb + (size_t)(r + 8) * NE);
      wn0 = (wn0 >> 1) | (v.x != 0.f ? top : 0);
      wn1 = (wn1 >> 1) | (v.y != 0.f ? top : 0);
    }
    #pragma unroll
    for (int r = 56; r < 64; ++r) {
      const float2 v = pf[r & 7];
      wn0 = (wn0 >> 1) | (v.x != 0.f ? top : 0);
      wn1 = (wn1 >> 1) | (v.y != 0.f ? top : 0);
    }
    *(ulonglong2*)bn = make_ulonglong2(wn0, wn1);      // e_nat, e_nat+1
    be[(size_t)(strip * 2 + 0) * NN] = bit_transpose64(wn0, l);
    be[(size_t)(strip * 2 + 1) * NN] = bit_transpose64(wn1, l);
  }
}

// ---------------------------------------------------------------------------
// K_edge2: D[e' 64][o 64] += H^T[e'][n] * x'[n][o]. (round-7 body; ONLY the
// enat line changed to match the new bitsE permutation.)
// ---------------------------------------------------------------------------
__global__ __launch_bounds__(256) void k_edge2(
    const u64* __restrict__ bitsN, const unsigned short* __restrict__ xt_blk,
    float* __restrict__ xe_part, float* __restrict__ deg_part) {
  const int ew = blockIdx.x, b = blockIdx.y, ks = blockIdx.z;
  const int tid = threadIdx.x, w = tid >> 6, l = tid & 63, q = l >> 5;
  __shared__ uint4 lut[256];
  LUT_INIT(lut)
  __syncthreads();
  const int erow = (w & 1) * 32 + (l & 31);
  const int ocol = (w >> 1) * 32 + (l & 31);
  const int enat = (ew >> 1) * 128 + 2 * erow + (ew & 1);   // NEW permutation
  const u64* Nb = bitsN + ((size_t)b * 128 + ks * 16) * NE + enat;
  const unsigned short* Bb =
      xt_blk + ((size_t)b * NW8 + ks * 128) * 512 + (size_t)ocol * 8;
  float* xo = xe_part + ((size_t)(ks * NB + b)) * (NE * NC) +
              (size_t)ew * 64 * NC + ocol;

  f32x16 acc;
  #pragma unroll
  for (int j = 0; j < 16; ++j) acc[j] = 0.f;
  int dcount = 0;
  for (int nt = 0; nt < 16; ++nt) {
    const u64 wbits = Nb[(size_t)nt * NE];
    dcount += __popcll(wbits);
    #pragma unroll
    for (int kk = 0; kk < 4; ++kk) {
      const bf16x8 av =
          *(const bf16x8*)&lut[(uint32_t)(wbits >> (8 * (kk * 2 + q))) & 0xFFu];
      const bf16x8 bv = ld_bf8(Bb + (size_t)(nt * 8 + kk * 2 + q) * 512);
      acc = __builtin_amdgcn_mfma_f32_32x32x16_bf16(av, bv, acc, 0, 0, 0);
    }
  }
  #pragma unroll
  for (int r = 0; r < 16; ++r) {
    const int rho = (w & 1) * 32 + 4 * q + (r & 3) + 8 * (r >> 2);
    xo[(size_t)rho * NC] = acc[r];
  }
  if (w < 2 && q == 0)
    deg_part[(size_t)(ks * NB + b) * NE + ew * 64 + erow] = (float)dcount;
}

// ---------------------------------------------------------------------------
// K_deg: deg_inv[b][e'] = 1 / sum_ks deg_part.  (unchanged)
// ---------------------------------------------------------------------------
__global__ __launch_bounds__(256) void k_deg(
    const float* __restrict__ deg_part, float* __restrict__ deg_inv) {
  const int idx = blockIdx.x * 256 + threadIdx.x;
  float s = 0.f;
  #pragma unroll
  for (int ks = 0; ks < KS2; ++ks) s += deg_part[(size_t)ks * (NB * NE) + idx];
  deg_inv[idx] = s > 0.f ? 1.0f / s : 0.f;
}

// ---------------------------------------------------------------------------
// K_edge_norm: xe_blk[b][e'>>3][o][e'&7] = bf16(sum_ks xe_part * deg_inv).
// (unchanged)
// ---------------------------------------------------------------------------
__global__ __launch_bounds__(256) void k_edge_norm(
    const float* __restrict__ xe_part, const float* __restrict__ deg_inv,
    unsigned short* __restrict__ xe_blk) {
  const int eb = blockIdx.x, b = blockIdx.y, tid = threadIdx.x;
  __shared__ unsigned short tt[64][72];
  const int o = tid & 63, eg = tid >> 6;
  #pragma unroll 4
  for (int j = 0; j < 16; ++j) {
    const int el = eg * 16 + j;
    const size_t idx = ((size_t)b * NE + eb * 64 + el) * NC + o;
    float s = 0.f;
    #pragma unroll
    for (int ks = 0; ks < KS2; ++ks) s += xe_part[(size_t)ks * (NB * NE * NC) + idx];
    tt[el][o] = f2bf(s * deg_inv[b * NE + eb * 64 + el]);
  }
  __syncthreads();
  unsigned short* obase = xe_blk + ((size_t)b * EW8 + eb * 8) * 512;
  for (int c = tid; c < 512; c += 256) {
    const int g = c >> 6, oo = c & 63;
    union { unsigned short s[8]; uint4 v; } pk;
    #pragma unroll
    for (int k = 0; k < 8; ++k) pk.s[k] = tt[g * 8 + k][oo];
    *(uint4*)(obase + (size_t)c * 8) = pk.v;
  }
}

// ---------------------------------------------------------------------------
// K_node2: D[n 64][o 64] += H[n][e'] * xe[e'][o]. (unchanged — operates
// purely in e' space, permutation-agnostic)
// ---------------------------------------------------------------------------
__global__ __launch_bounds__(256) void k_node2(
    const u64* __restrict__ bitsE, const unsigned short* __restrict__ xe_blk,
    const float* __restrict__ bias, float* __restrict__ out) {
  const int ns = blockIdx.x, b = blockIdx.y;
  const int n0 = ns * 64;
  const int tid = threadIdx.x, w = tid >> 6, l = tid & 63, q = l >> 5;
  __shared__ uint4 lut[256];
  __shared__ float ldsDeg[64];
  LUT_INIT(lut)
  const int arow = (w & 1) * 32 + (l & 31);
  const int ocol = (w >> 1) * 32 + (l & 31);
  const u64* Eb = bitsE + (size_t)b * 32 * NN + n0 + arow;
  const unsigned short* Bb = xe_blk + (size_t)b * EW8 * 512 + (size_t)ocol * 8;
  __syncthreads();

  f32x16 acc;
  #pragma unroll
  for (int j = 0; j < 16; ++j) acc[j] = 0.f;
  int dcount = 0;
  for (int et = 0; et < 32; ++et) {
    const u64 wbits = Eb[(size_t)et * NN];
    dcount += __popcll(wbits);
    #pragma unroll
    for (int kk = 0; kk < 4; ++kk) {
      const bf16x8 av =
          *(const bf16x8*)&lut[(uint32_t)(wbits >> (8 * (kk * 2 + q))) & 0xFFu];
      const bf16x8 bv = ld_bf8(Bb + (size_t)(et * 8 + kk * 2 + q) * 512);
      acc = __builtin_amdgcn_mfma_f32_32x32x16_bf16(av, bv, acc, 0, 0, 0);
    }
  }
  if (w < 2 && q == 0) ldsDeg[arow] = dcount > 0 ? 1.0f / (float)dcount : 0.f;
  __syncthreads();
  const float bv0 = bias[ocol];
  #pragma unroll
  for (int r = 0; r < 16; ++r) {
    const int rho = (w & 1) * 32 + 4 * q + (r & 3) + 8 * (r >> 2);
    out[((size_t)b * NN + n0 + rho) * NC + ocol] = acc[r] * ldsDeg[rho] + bv0;
  }
}

// ---------------------------------------------------------------------------
// ws: xt_blk @0 (4MB) | bitsN @4MB (8MB) | bitsE @12MB (8MB) | xe_part @20MB
// (16MB) | deg_part @36MB (256KB) | deg_inv @+256KB (32KB) | xe_blk @37MB (1MB)
// ---------------------------------------------------------------------------
extern "C" void kernel_launch(void* const* d_in, const int* in_sizes, int n_in,
                              void* d_out, int out_size, void* d_ws, size_t ws_size,
                              hipStream_t stream) {
  const float* x     = (const float*)d_in[0];
  const float* H     = (const float*)d_in[1];
  const float* theta = (const float*)d_in[2];
  const float* bias  = (const float*)d_in[3];
  float* out = (float*)d_out;
  char* ws = (char*)d_ws;

  unsigned short* xt_blk = (unsigned short*)ws;
  u64* bitsN             = (u64*)(ws + (4ull << 20));
  u64* bitsE             = (u64*)(ws + (12ull << 20));
  float* xe_part         = (float*)(ws + (20ull << 20));
  float* deg_part        = (float*)(ws + (36ull << 20));
  float* deg_inv         = (float*)(ws + (36ull << 20) + (256ull << 10));
  unsigned short* xe_blk = (unsigned short*)(ws + (37ull << 20));

  k_transform<<<dim3(NN / 64, NB), 256, 0, stream>>>(x, theta, xt_blk);
  k_pack<<<dim3((NN / 64) * 4, NB), 256, 0, stream>>>(H, bitsN, bitsE);
  k_edge2<<<dim3(32, NB, KS2), 256, 0, stream>>>(bitsN, xt_blk, xe_part, deg_part);
  k_deg<<<dim3((NB * NE) / 256), 256, 0, stream>>>(deg_part, deg_inv);
  k_edge_norm<<<dim3(NE / 64, NB), 256, 0, stream>>>(xe_part, deg_inv, xe_blk);
  k_node2<<<dim3(NN / 64, NB), 256, 0, stream>>>(bitsE, xe_blk, bias, out);
}

// Round 9
// 114.314 us; speedup vs baseline: 9.3146x; 1.3734x over previous
//
// ============================================================================
// Round 9: REP instrumentation stripped (k_pack runs once). All kernel bodies
// byte-identical to the passing round-8 build otherwise.
// Pipeline: x@theta (fp32->bf16 blocked) | H->bitpack both orientations |
// MFMA edge-agg via LDS-LUT bit expand | deg normalize | MFMA node-agg.
// ============================================================================
#include <hip/hip_runtime.h>
#include <stdint.h>

#define NB 4
#define NN 8192
#define NE 2048
#define NC 64
#define KS2 8              // n-split for k_edge2
#define NW8 (NN / 8)       // 1024 blocked-n groups
#define EW8 (NE / 8)       // 256 blocked-e groups

typedef __bf16 bf16x8 __attribute__((ext_vector_type(8)));
typedef float f32x16 __attribute__((ext_vector_type(16)));
typedef unsigned long long u64;

__device__ __forceinline__ unsigned short f2bf(float f) {
  union { float f; uint32_t u; } v; v.f = f;
  return (unsigned short)((v.u + 0x7FFFu + ((v.u >> 16) & 1u)) >> 16);
}
__device__ __forceinline__ bf16x8 ld_bf8(const void* p) { return *(const bf16x8*)p; }

// in-register 64x64 bit-matrix transpose across the wave
__device__ __forceinline__ u64 bt_step(u64 x, int k, u64 M1, int lane) {
  const u64 y = (u64)__shfl_xor((long long)x, k, 64);
  const u64 M0 = ~M1;
  return ((lane & k) == 0) ? ((x & M0) | ((y & M0) << k))
                           : ((x & M1) | ((y >> k) & M0));
}
__device__ __forceinline__ u64 bit_transpose64(u64 x, int lane) {
  x = bt_step(x, 1,  0xAAAAAAAAAAAAAAAAull, lane);
  x = bt_step(x, 2,  0xCCCCCCCCCCCCCCCCull, lane);
  x = bt_step(x, 4,  0xF0F0F0F0F0F0F0F0ull, lane);
  x = bt_step(x, 8,  0xFF00FF00FF00FF00ull, lane);
  x = bt_step(x, 16, 0xFFFF0000FFFF0000ull, lane);
  x = bt_step(x, 32, 0xFFFFFFFF00000000ull, lane);
  return x;
}

// 256-entry LDS LUT: byte -> 8 bf16 of 0.0/1.0 (16B).
#define LUT_INIT(lut)                                                     \
  {                                                                       \
    union { uint32_t u[4]; uint4 v; } e_;                                 \
    const uint32_t by_ = threadIdx.x & 255;                               \
    _Pragma("unroll")                                                     \
    for (int p_ = 0; p_ < 4; ++p_) {                                      \
      const uint32_t t_ = (by_ >> (2 * p_)) & 3u;                         \
      e_.u[p_] = (t_ & 1u) * 0x3F80u + (t_ & 2u) * 0x1FC00000u;           \
    }                                                                     \
    lut[by_] = e_.v;                                                      \
  }

// ---------------------------------------------------------------------------
// K1: x' = x @ theta (fp32), output BLOCKED bf16: xt_blk[b][n>>3][o][n&7].
// ---------------------------------------------------------------------------
__global__ __launch_bounds__(256) void k_transform(
    const float* __restrict__ x, const float* __restrict__ theta,
    unsigned short* __restrict__ xt_blk) {
  const int b = blockIdx.y, ns = blockIdx.x;
  const int n0 = ns * 64;
  __shared__ float xs[64][65];
  __shared__ float th[64][64];
  const int tid = threadIdx.x, w = tid >> 6, l = tid & 63;
  for (int k = tid; k < 4096; k += 256) th[k >> 6][k & 63] = theta[k];
  const float* xrow = x + ((size_t)b * NN + n0) * NC;
  for (int k = tid; k < 4096; k += 256) xs[k >> 6][k & 63] = xrow[k];
  __syncthreads();
  float acc[16];
  #pragma unroll
  for (int j = 0; j < 16; ++j) acc[j] = 0.f;
  #pragma unroll 4
  for (int i = 0; i < 64; ++i) {
    const float xv = xs[l][i];
    const float4* t4 = (const float4*)(&th[i][w * 16]);
    const float4 a0 = t4[0], a1 = t4[1], a2 = t4[2], a3 = t4[3];
    acc[0]  += xv * a0.x; acc[1]  += xv * a0.y; acc[2]  += xv * a0.z; acc[3]  += xv * a0.w;
    acc[4]  += xv * a1.x; acc[5]  += xv * a1.y; acc[6]  += xv * a1.z; acc[7]  += xv * a1.w;
    acc[8]  += xv * a2.x; acc[9]  += xv * a2.y; acc[10] += xv * a2.z; acc[11] += xv * a2.w;
    acc[12] += xv * a3.x; acc[13] += xv * a3.y; acc[14] += xv * a3.z; acc[15] += xv * a3.w;
  }
  __syncthreads();                       // xs reads complete
  unsigned short* ost = (unsigned short*)&xs[0][0];   // reuse as [n][o] u16
  #pragma unroll
  for (int j = 0; j < 16; ++j) ost[l * 64 + w * 16 + j] = f2bf(acc[j]);
  __syncthreads();
  unsigned short* obase = xt_blk + ((size_t)b * NW8 + ns * 8) * 512;
  for (int c = tid; c < 512; c += 256) {   // c = g*64 + o
    const int g = c >> 6, o = c & 63;
    union { unsigned short s[8]; uint4 v; } pk;
    #pragma unroll
    for (int k = 0; k < 8; ++k) pk.s[k] = ost[(g * 8 + k) * 64 + o];
    *(uint4*)(obase + (size_t)c * 8) = pk.v;
  }
}

// ---------------------------------------------------------------------------
// K_pack: streams H once. Grid 2048 blocks (8/CU): block = 64 rows x 512
// e-floats; wave = 128-float strip; lane = float2/row, 8-row prefetch.
// Emits bitsN[b][nw][e_nat] and bitsE[b][ew'][n],
// e' permutation: e_nat = (ew'>>1)*128 + 2*bit + (ew'&1).
// ---------------------------------------------------------------------------
__global__ __launch_bounds__(256) void k_pack(
    const float* __restrict__ H, u64* __restrict__ bitsN,
    u64* __restrict__ bitsE) {
  const int ns = blockIdx.x >> 2, eh = blockIdx.x & 3, b = blockIdx.y;
  const int w = threadIdx.x >> 6, l = threadIdx.x & 63;
  const int n0 = ns * 64;
  const int strip = eh * 4 + w;              // global 128-float strip [0,16)
  const float* Hb = H + ((size_t)b * NN + n0) * NE + strip * 128 + 2 * l;
  u64* bn = bitsN + ((size_t)b * 128 + ns) * NE + strip * 128 + 2 * l;
  u64* be = bitsE + (size_t)b * 32 * NN + n0 + l;
  const u64 top = 0x8000000000000000ull;

  u64 wn0 = 0, wn1 = 0;
  float2 pf[8];
  #pragma unroll
  for (int j = 0; j < 8; ++j) pf[j] = *(const float2*)(Hb + (size_t)j * NE);
  #pragma unroll 8
  for (int r = 0; r < 56; ++r) {
    const float2 v = pf[r & 7];
    pf[r & 7] = *(const float2*)(Hb + (size_t)(r + 8) * NE);
    wn0 = (wn0 >> 1) | (v.x != 0.f ? top : 0);
    wn1 = (wn1 >> 1) | (v.y != 0.f ? top : 0);
  }
  #pragma unroll
  for (int r = 56; r < 64; ++r) {
    const float2 v = pf[r & 7];
    wn0 = (wn0 >> 1) | (v.x != 0.f ? top : 0);
    wn1 = (wn1 >> 1) | (v.y != 0.f ? top : 0);
  }
  *(ulonglong2*)bn = make_ulonglong2(wn0, wn1);      // e_nat, e_nat+1
  be[(size_t)(strip * 2 + 0) * NN] = bit_transpose64(wn0, l);
  be[(size_t)(strip * 2 + 1) * NN] = bit_transpose64(wn1, l);
}

// ---------------------------------------------------------------------------
// K_edge2: D[e' 64][o 64] += H^T[e'][n] * x'[n][o].  A = bitsN via LDS-LUT,
// B = xt_blk contiguous 16B frags. deg_e via popcount.
// ---------------------------------------------------------------------------
__global__ __launch_bounds__(256) void k_edge2(
    const u64* __restrict__ bitsN, const unsigned short* __restrict__ xt_blk,
    float* __restrict__ xe_part, float* __restrict__ deg_part) {
  const int ew = blockIdx.x, b = blockIdx.y, ks = blockIdx.z;
  const int tid = threadIdx.x, w = tid >> 6, l = tid & 63, q = l >> 5;
  __shared__ uint4 lut[256];
  LUT_INIT(lut)
  __syncthreads();
  const int erow = (w & 1) * 32 + (l & 31);
  const int ocol = (w >> 1) * 32 + (l & 31);
  const int enat = (ew >> 1) * 128 + 2 * erow + (ew & 1);
  const u64* Nb = bitsN + ((size_t)b * 128 + ks * 16) * NE + enat;
  const unsigned short* Bb =
      xt_blk + ((size_t)b * NW8 + ks * 128) * 512 + (size_t)ocol * 8;
  float* xo = xe_part + ((size_t)(ks * NB + b)) * (NE * NC) +
              (size_t)ew * 64 * NC + ocol;

  f32x16 acc;
  #pragma unroll
  for (int j = 0; j < 16; ++j) acc[j] = 0.f;
  int dcount = 0;
  for (int nt = 0; nt < 16; ++nt) {
    const u64 wbits = Nb[(size_t)nt * NE];
    dcount += __popcll(wbits);
    #pragma unroll
    for (int kk = 0; kk < 4; ++kk) {
      const bf16x8 av =
          *(const bf16x8*)&lut[(uint32_t)(wbits >> (8 * (kk * 2 + q))) & 0xFFu];
      const bf16x8 bv = ld_bf8(Bb + (size_t)(nt * 8 + kk * 2 + q) * 512);
      acc = __builtin_amdgcn_mfma_f32_32x32x16_bf16(av, bv, acc, 0, 0, 0);
    }
  }
  #pragma unroll
  for (int r = 0; r < 16; ++r) {
    const int rho = (w & 1) * 32 + 4 * q + (r & 3) + 8 * (r >> 2);
    xo[(size_t)rho * NC] = acc[r];
  }
  if (w < 2 && q == 0)
    deg_part[(size_t)(ks * NB + b) * NE + ew * 64 + erow] = (float)dcount;
}

// ---------------------------------------------------------------------------
// K_deg: deg_inv[b][e'] = 1 / sum_ks deg_part.
// ---------------------------------------------------------------------------
__global__ __launch_bounds__(256) void k_deg(
    const float* __restrict__ deg_part, float* __restrict__ deg_inv) {
  const int idx = blockIdx.x * 256 + threadIdx.x;
  float s = 0.f;
  #pragma unroll
  for (int ks = 0; ks < KS2; ++ks) s += deg_part[(size_t)ks * (NB * NE) + idx];
  deg_inv[idx] = s > 0.f ? 1.0f / s : 0.f;
}

// ---------------------------------------------------------------------------
// K_edge_norm: xe_blk[b][e'>>3][o][e'&7] = bf16(sum_ks xe_part * deg_inv).
// ---------------------------------------------------------------------------
__global__ __launch_bounds__(256) void k_edge_norm(
    const float* __restrict__ xe_part, const float* __restrict__ deg_inv,
    unsigned short* __restrict__ xe_blk) {
  const int eb = blockIdx.x, b = blockIdx.y, tid = threadIdx.x;
  __shared__ unsigned short tt[64][72];
  const int o = tid & 63, eg = tid >> 6;
  #pragma unroll 4
  for (int j = 0; j < 16; ++j) {
    const int el = eg * 16 + j;
    const size_t idx = ((size_t)b * NE + eb * 64 + el) * NC + o;
    float s = 0.f;
    #pragma unroll
    for (int ks = 0; ks < KS2; ++ks) s += xe_part[(size_t)ks * (NB * NE * NC) + idx];
    tt[el][o] = f2bf(s * deg_inv[b * NE + eb * 64 + el]);
  }
  __syncthreads();
  unsigned short* obase = xe_blk + ((size_t)b * EW8 + eb * 8) * 512;
  for (int c = tid; c < 512; c += 256) {
    const int g = c >> 6, oo = c & 63;
    union { unsigned short s[8]; uint4 v; } pk;
    #pragma unroll
    for (int k = 0; k < 8; ++k) pk.s[k] = tt[g * 8 + k][oo];
    *(uint4*)(obase + (size_t)c * 8) = pk.v;
  }
}

// ---------------------------------------------------------------------------
// K_node2: D[n 64][o 64] += H[n][e'] * xe[e'][o].  A = bitsE via LDS-LUT,
// B = xe_blk contiguous frags. deg_n via popcount.
// ---------------------------------------------------------------------------
__global__ __launch_bounds__(256) void k_node2(
    const u64* __restrict__ bitsE, const unsigned short* __restrict__ xe_blk,
    const float* __restrict__ bias, float* __restrict__ out) {
  const int ns = blockIdx.x, b = blockIdx.y;
  const int n0 = ns * 64;
  const int tid = threadIdx.x, w = tid >> 6, l = tid & 63, q = l >> 5;
  __shared__ uint4 lut[256];
  __shared__ float ldsDeg[64];
  LUT_INIT(lut)
  const int arow = (w & 1) * 32 + (l & 31);
  const int ocol = (w >> 1) * 32 + (l & 31);
  const u64* Eb = bitsE + (size_t)b * 32 * NN + n0 + arow;
  const unsigned short* Bb = xe_blk + (size_t)b * EW8 * 512 + (size_t)ocol * 8;
  __syncthreads();

  f32x16 acc;
  #pragma unroll
  for (int j = 0; j < 16; ++j) acc[j] = 0.f;
  int dcount = 0;
  for (int et = 0; et < 32; ++et) {
    const u64 wbits = Eb[(size_t)et * NN];
    dcount += __popcll(wbits);
    #pragma unroll
    for (int kk = 0; kk < 4; ++kk) {
      const bf16x8 av =
          *(const bf16x8*)&lut[(uint32_t)(wbits >> (8 * (kk * 2 + q))) & 0xFFu];
      const bf16x8 bv = ld_bf8(Bb + (size_t)(et * 8 + kk * 2 + q) * 512);
      acc = __builtin_amdgcn_mfma_f32_32x32x16_bf16(av, bv, acc, 0, 0, 0);
    }
  }
  if (w < 2 && q == 0) ldsDeg[arow] = dcount > 0 ? 1.0f / (float)dcount : 0.f;
  __syncthreads();
  const float bv0 = bias[ocol];
  #pragma unroll
  for (int r = 0; r < 16; ++r) {
    const int rho = (w & 1) * 32 + 4 * q + (r & 3) + 8 * (r >> 2);
    out[((size_t)b * NN + n0 + rho) * NC + ocol] = acc[r] * ldsDeg[rho] + bv0;
  }
}

// ---------------------------------------------------------------------------
// ws: xt_blk @0 (4MB) | bitsN @4MB (8MB) | bitsE @12MB (8MB) | xe_part @20MB
// (16MB) | deg_part @36MB (256KB) | deg_inv @+256KB (32KB) | xe_blk @37MB (1MB)
// ---------------------------------------------------------------------------
extern "C" void kernel_launch(void* const* d_in, const int* in_sizes, int n_in,
                              void* d_out, int out_size, void* d_ws, size_t ws_size,
                              hipStream_t stream) {
  const float* x     = (const float*)d_in[0];
  const float* H     = (const float*)d_in[1];
  const float* theta = (const float*)d_in[2];
  const float* bias  = (const float*)d_in[3];
  float* out = (float*)d_out;
  char* ws = (char*)d_ws;

  unsigned short* xt_blk = (unsigned short*)ws;
  u64* bitsN             = (u64*)(ws + (4ull << 20));
  u64* bitsE             = (u64*)(ws + (12ull << 20));
  float* xe_part         = (float*)(ws + (20ull << 20));
  float* deg_part        = (float*)(ws + (36ull << 20));
  float* deg_inv         = (float*)(ws + (36ull << 20) + (256ull << 10));
  unsigned short* xe_blk = (unsigned short*)(ws + (37ull << 20));

  k_transform<<<dim3(NN / 64, NB), 256, 0, stream>>>(x, theta, xt_blk);
  k_pack<<<dim3((NN / 64) * 4, NB), 256, 0, stream>>>(H, bitsN, bitsE);
  k_edge2<<<dim3(32, NB, KS2), 256, 0, stream>>>(bitsN, xt_blk, xe_part, deg_part);
  k_deg<<<dim3((NB * NE) / 256), 256, 0, stream>>>(deg_part, deg_inv);
  k_edge_norm<<<dim3(NE / 64, NB), 256, 0, stream>>>(xe_part, deg_inv, xe_blk);
  k_node2<<<dim3(NN / 64, NB), 256, 0, stream>>>(bitsE, xe_blk, bias, out);
}

// Round 10
// 98.822 us; speedup vs baseline: 10.7749x; 1.1568x over previous
//
// ============================================================================
// Round 10: latency-chain attack. (1) k_node2/k_edge2: batch-prefetch ALL
// wbits u64 loads up front (independent, issued back-to-back -> single
// latency fill instead of per-iteration serial stalls; accumulation order
// unchanged -> bitwise-identical output). (2) k_deg fused into k_edge_norm
// (same ks summation order -> bitwise identical). 5 launches.
// ============================================================================
#include <hip/hip_runtime.h>
#include <stdint.h>

#define NB 4
#define NN 8192
#define NE 2048
#define NC 64
#define KS2 8              // n-split for k_edge2
#define NW8 (NN / 8)       // 1024 blocked-n groups
#define EW8 (NE / 8)       // 256 blocked-e groups

typedef __bf16 bf16x8 __attribute__((ext_vector_type(8)));
typedef float f32x16 __attribute__((ext_vector_type(16)));
typedef unsigned long long u64;

__device__ __forceinline__ unsigned short f2bf(float f) {
  union { float f; uint32_t u; } v; v.f = f;
  return (unsigned short)((v.u + 0x7FFFu + ((v.u >> 16) & 1u)) >> 16);
}
__device__ __forceinline__ bf16x8 ld_bf8(const void* p) { return *(const bf16x8*)p; }

// in-register 64x64 bit-matrix transpose across the wave
__device__ __forceinline__ u64 bt_step(u64 x, int k, u64 M1, int lane) {
  const u64 y = (u64)__shfl_xor((long long)x, k, 64);
  const u64 M0 = ~M1;
  return ((lane & k) == 0) ? ((x & M0) | ((y & M0) << k))
                           : ((x & M1) | ((y >> k) & M0));
}
__device__ __forceinline__ u64 bit_transpose64(u64 x, int lane) {
  x = bt_step(x, 1,  0xAAAAAAAAAAAAAAAAull, lane);
  x = bt_step(x, 2,  0xCCCCCCCCCCCCCCCCull, lane);
  x = bt_step(x, 4,  0xF0F0F0F0F0F0F0F0ull, lane);
  x = bt_step(x, 8,  0xFF00FF00FF00FF00ull, lane);
  x = bt_step(x, 16, 0xFFFF0000FFFF0000ull, lane);
  x = bt_step(x, 32, 0xFFFFFFFF00000000ull, lane);
  return x;
}

// 256-entry LDS LUT: byte -> 8 bf16 of 0.0/1.0 (16B).
#define LUT_INIT(lut)                                                     \
  {                                                                       \
    union { uint32_t u[4]; uint4 v; } e_;                                 \
    const uint32_t by_ = threadIdx.x & 255;                               \
    _Pragma("unroll")                                                     \
    for (int p_ = 0; p_ < 4; ++p_) {                                      \
      const uint32_t t_ = (by_ >> (2 * p_)) & 3u;                         \
      e_.u[p_] = (t_ & 1u) * 0x3F80u + (t_ & 2u) * 0x1FC00000u;           \
    }                                                                     \
    lut[by_] = e_.v;                                                      \
  }

// ---------------------------------------------------------------------------
// K1: x' = x @ theta (fp32), output BLOCKED bf16: xt_blk[b][n>>3][o][n&7].
// (unchanged)
// ---------------------------------------------------------------------------
__global__ __launch_bounds__(256) void k_transform(
    const float* __restrict__ x, const float* __restrict__ theta,
    unsigned short* __restrict__ xt_blk) {
  const int b = blockIdx.y, ns = blockIdx.x;
  const int n0 = ns * 64;
  __shared__ float xs[64][65];
  __shared__ float th[64][64];
  const int tid = threadIdx.x, w = tid >> 6, l = tid & 63;
  for (int k = tid; k < 4096; k += 256) th[k >> 6][k & 63] = theta[k];
  const float* xrow = x + ((size_t)b * NN + n0) * NC;
  for (int k = tid; k < 4096; k += 256) xs[k >> 6][k & 63] = xrow[k];
  __syncthreads();
  float acc[16];
  #pragma unroll
  for (int j = 0; j < 16; ++j) acc[j] = 0.f;
  #pragma unroll 4
  for (int i = 0; i < 64; ++i) {
    const float xv = xs[l][i];
    const float4* t4 = (const float4*)(&th[i][w * 16]);
    const float4 a0 = t4[0], a1 = t4[1], a2 = t4[2], a3 = t4[3];
    acc[0]  += xv * a0.x; acc[1]  += xv * a0.y; acc[2]  += xv * a0.z; acc[3]  += xv * a0.w;
    acc[4]  += xv * a1.x; acc[5]  += xv * a1.y; acc[6]  += xv * a1.z; acc[7]  += xv * a1.w;
    acc[8]  += xv * a2.x; acc[9]  += xv * a2.y; acc[10] += xv * a2.z; acc[11] += xv * a2.w;
    acc[12] += xv * a3.x; acc[13] += xv * a3.y; acc[14] += xv * a3.z; acc[15] += xv * a3.w;
  }
  __syncthreads();                       // xs reads complete
  unsigned short* ost = (unsigned short*)&xs[0][0];   // reuse as [n][o] u16
  #pragma unroll
  for (int j = 0; j < 16; ++j) ost[l * 64 + w * 16 + j] = f2bf(acc[j]);
  __syncthreads();
  unsigned short* obase = xt_blk + ((size_t)b * NW8 + ns * 8) * 512;
  for (int c = tid; c < 512; c += 256) {   // c = g*64 + o
    const int g = c >> 6, o = c & 63;
    union { unsigned short s[8]; uint4 v; } pk;
    #pragma unroll
    for (int k = 0; k < 8; ++k) pk.s[k] = ost[(g * 8 + k) * 64 + o];
    *(uint4*)(obase + (size_t)c * 8) = pk.v;
  }
}

// ---------------------------------------------------------------------------
// K_pack: streams H once. Grid 2048 blocks (8/CU). (unchanged)
// e' permutation: e_nat = (ew'>>1)*128 + 2*bit + (ew'&1).
// ---------------------------------------------------------------------------
__global__ __launch_bounds__(256) void k_pack(
    const float* __restrict__ H, u64* __restrict__ bitsN,
    u64* __restrict__ bitsE) {
  const int ns = blockIdx.x >> 2, eh = blockIdx.x & 3, b = blockIdx.y;
  const int w = threadIdx.x >> 6, l = threadIdx.x & 63;
  const int n0 = ns * 64;
  const int strip = eh * 4 + w;              // global 128-float strip [0,16)
  const float* Hb = H + ((size_t)b * NN + n0) * NE + strip * 128 + 2 * l;
  u64* bn = bitsN + ((size_t)b * 128 + ns) * NE + strip * 128 + 2 * l;
  u64* be = bitsE + (size_t)b * 32 * NN + n0 + l;
  const u64 top = 0x8000000000000000ull;

  u64 wn0 = 0, wn1 = 0;
  float2 pf[8];
  #pragma unroll
  for (int j = 0; j < 8; ++j) pf[j] = *(const float2*)(Hb + (size_t)j * NE);
  #pragma unroll 8
  for (int r = 0; r < 56; ++r) {
    const float2 v = pf[r & 7];
    pf[r & 7] = *(const float2*)(Hb + (size_t)(r + 8) * NE);
    wn0 = (wn0 >> 1) | (v.x != 0.f ? top : 0);
    wn1 = (wn1 >> 1) | (v.y != 0.f ? top : 0);
  }
  #pragma unroll
  for (int r = 56; r < 64; ++r) {
    const float2 v = pf[r & 7];
    wn0 = (wn0 >> 1) | (v.x != 0.f ? top : 0);
    wn1 = (wn1 >> 1) | (v.y != 0.f ? top : 0);
  }
  *(ulonglong2*)bn = make_ulonglong2(wn0, wn1);      // e_nat, e_nat+1
  be[(size_t)(strip * 2 + 0) * NN] = bit_transpose64(wn0, l);
  be[(size_t)(strip * 2 + 1) * NN] = bit_transpose64(wn1, l);
}

// ---------------------------------------------------------------------------
// K_edge2: D[e' 64][o 64] += H^T[e'][n] * x'[n][o].  All 16 wbits u64 loads
// issued up front (independent -> one latency fill); accumulation order
// unchanged. A = bitsN via LDS-LUT, B = xt_blk 16B frags.
// ---------------------------------------------------------------------------
__global__ __launch_bounds__(256) void k_edge2(
    const u64* __restrict__ bitsN, const unsigned short* __restrict__ xt_blk,
    float* __restrict__ xe_part, float* __restrict__ deg_part) {
  const int ew = blockIdx.x, b = blockIdx.y, ks = blockIdx.z;
  const int tid = threadIdx.x, w = tid >> 6, l = tid & 63, q = l >> 5;
  __shared__ uint4 lut[256];
  LUT_INIT(lut)
  __syncthreads();
  const int erow = (w & 1) * 32 + (l & 31);
  const int ocol = (w >> 1) * 32 + (l & 31);
  const int enat = (ew >> 1) * 128 + 2 * erow + (ew & 1);
  const u64* Nb = bitsN + ((size_t)b * 128 + ks * 16) * NE + enat;
  const unsigned short* Bb =
      xt_blk + ((size_t)b * NW8 + ks * 128) * 512 + (size_t)ocol * 8;
  float* xo = xe_part + ((size_t)(ks * NB + b)) * (NE * NC) +
              (size_t)ew * 64 * NC + ocol;

  u64 wb[16];
  #pragma unroll
  for (int nt = 0; nt < 16; ++nt) wb[nt] = Nb[(size_t)nt * NE];

  f32x16 acc;
  #pragma unroll
  for (int j = 0; j < 16; ++j) acc[j] = 0.f;
  int dcount = 0;
  #pragma unroll
  for (int nt = 0; nt < 16; ++nt) {
    const u64 wbits = wb[nt];
    dcount += __popcll(wbits);
    #pragma unroll
    for (int kk = 0; kk < 4; ++kk) {
      const bf16x8 av =
          *(const bf16x8*)&lut[(uint32_t)(wbits >> (8 * (kk * 2 + q))) & 0xFFu];
      const bf16x8 bv = ld_bf8(Bb + (size_t)(nt * 8 + kk * 2 + q) * 512);
      acc = __builtin_amdgcn_mfma_f32_32x32x16_bf16(av, bv, acc, 0, 0, 0);
    }
  }
  #pragma unroll
  for (int r = 0; r < 16; ++r) {
    const int rho = (w & 1) * 32 + 4 * q + (r & 3) + 8 * (r >> 2);
    xo[(size_t)rho * NC] = acc[r];
  }
  if (w < 2 && q == 0)
    deg_part[(size_t)(ks * NB + b) * NE + ew * 64 + erow] = (float)dcount;
}

// ---------------------------------------------------------------------------
// K_edge_norm (+fused deg): dinv computed per-block in LDS (same ks order as
// the old k_deg -> bitwise identical), then
// xe_blk[b][e'>>3][o][e'&7] = bf16(sum_ks xe_part * dinv).
// ---------------------------------------------------------------------------
__global__ __launch_bounds__(256) void k_edge_norm(
    const float* __restrict__ xe_part, const float* __restrict__ deg_part,
    unsigned short* __restrict__ xe_blk) {
  const int eb = blockIdx.x, b = blockIdx.y, tid = threadIdx.x;
  __shared__ unsigned short tt[64][72];
  __shared__ float dinv[64];
  if (tid < 64) {
    float s = 0.f;
    #pragma unroll
    for (int ks = 0; ks < KS2; ++ks)
      s += deg_part[(size_t)ks * (NB * NE) + b * NE + eb * 64 + tid];
    dinv[tid] = s > 0.f ? 1.0f / s : 0.f;
  }
  __syncthreads();
  const int o = tid & 63, eg = tid >> 6;
  #pragma unroll 4
  for (int j = 0; j < 16; ++j) {
    const int el = eg * 16 + j;
    const size_t idx = ((size_t)b * NE + eb * 64 + el) * NC + o;
    float s = 0.f;
    #pragma unroll
    for (int ks = 0; ks < KS2; ++ks) s += xe_part[(size_t)ks * (NB * NE * NC) + idx];
    tt[el][o] = f2bf(s * dinv[el]);
  }
  __syncthreads();
  unsigned short* obase = xe_blk + ((size_t)b * EW8 + eb * 8) * 512;
  for (int c = tid; c < 512; c += 256) {
    const int g = c >> 6, oo = c & 63;
    union { unsigned short s[8]; uint4 v; } pk;
    #pragma unroll
    for (int k = 0; k < 8; ++k) pk.s[k] = tt[g * 8 + k][oo];
    *(uint4*)(obase + (size_t)c * 8) = pk.v;
  }
}

// ---------------------------------------------------------------------------
// K_node2: D[n 64][o 64] += H[n][e'] * xe[e'][o].  All 32 wbits u64 loads
// issued up front (64 VGPR — grid caps occupancy at 8 waves/CU, so VGPR is
// free); accumulation order unchanged. A = bitsE via LDS-LUT, B = xe_blk.
// ---------------------------------------------------------------------------
__global__ __launch_bounds__(256) void k_node2(
    const u64* __restrict__ bitsE, const unsigned short* __restrict__ xe_blk,
    const float* __restrict__ bias, float* __restrict__ out) {
  const int ns = blockIdx.x, b = blockIdx.y;
  const int n0 = ns * 64;
  const int tid = threadIdx.x, w = tid >> 6, l = tid & 63, q = l >> 5;
  __shared__ uint4 lut[256];
  __shared__ float ldsDeg[64];
  LUT_INIT(lut)
  const int arow = (w & 1) * 32 + (l & 31);
  const int ocol = (w >> 1) * 32 + (l & 31);
  const u64* Eb = bitsE + (size_t)b * 32 * NN + n0 + arow;
  const unsigned short* Bb = xe_blk + (size_t)b * EW8 * 512 + (size_t)ocol * 8;
  __syncthreads();

  u64 wb[32];
  #pragma unroll
  for (int et = 0; et < 32; ++et) wb[et] = Eb[(size_t)et * NN];

  f32x16 acc;
  #pragma unroll
  for (int j = 0; j < 16; ++j) acc[j] = 0.f;
  int dcount = 0;
  #pragma unroll
  for (int et = 0; et < 32; ++et) {
    const u64 wbits = wb[et];
    dcount += __popcll(wbits);
    #pragma unroll
    for (int kk = 0; kk < 4; ++kk) {
      const bf16x8 av =
          *(const bf16x8*)&lut[(uint32_t)(wbits >> (8 * (kk * 2 + q))) & 0xFFu];
      const bf16x8 bv = ld_bf8(Bb + (size_t)(et * 8 + kk * 2 + q) * 512);
      acc = __builtin_amdgcn_mfma_f32_32x32x16_bf16(av, bv, acc, 0, 0, 0);
    }
  }
  if (w < 2 && q == 0) ldsDeg[arow] = dcount > 0 ? 1.0f / (float)dcount : 0.f;
  __syncthreads();
  const float bv0 = bias[ocol];
  #pragma unroll
  for (int r = 0; r < 16; ++r) {
    const int rho = (w & 1) * 32 + 4 * q + (r & 3) + 8 * (r >> 2);
    out[((size_t)b * NN + n0 + rho) * NC + ocol] = acc[r] * ldsDeg[rho] + bv0;
  }
}

// ---------------------------------------------------------------------------
// ws: xt_blk @0 (4MB) | bitsN @4MB (8MB) | bitsE @12MB (8MB) | xe_part @20MB
// (16MB) | deg_part @36MB (256KB) | xe_blk @37MB (1MB)
// ---------------------------------------------------------------------------
extern "C" void kernel_launch(void* const* d_in, const int* in_sizes, int n_in,
                              void* d_out, int out_size, void* d_ws, size_t ws_size,
                              hipStream_t stream) {
  const float* x     = (const float*)d_in[0];
  const float* H     = (const float*)d_in[1];
  const float* theta = (const float*)d_in[2];
  const float* bias  = (const float*)d_in[3];
  float* out = (float*)d_out;
  char* ws = (char*)d_ws;

  unsigned short* xt_blk = (unsigned short*)ws;
  u64* bitsN             = (u64*)(ws + (4ull << 20));
  u64* bitsE             = (u64*)(ws + (12ull << 20));
  float* xe_part         = (float*)(ws + (20ull << 20));
  float* deg_part        = (float*)(ws + (36ull << 20));
  unsigned short* xe_blk = (unsigned short*)(ws + (37ull << 20));

  k_transform<<<dim3(NN / 64, NB), 256, 0, stream>>>(x, theta, xt_blk);
  k_pack<<<dim3((NN / 64) * 4, NB), 256, 0, stream>>>(H, bitsN, bitsE);
  k_edge2<<<dim3(32, NB, KS2), 256, 0, stream>>>(bitsN, xt_blk, xe_part, deg_part);
  k_edge_norm<<<dim3(NE / 64, NB), 256, 0, stream>>>(xe_part, deg_part, xe_blk);
  k_node2<<<dim3(NN / 64, NB), 256, 0, stream>>>(bitsE, xe_blk, bias, out);
}